// Round 13
// baseline (208.608 us; speedup 1.0000x reference)
//
#include <hip/hip_runtime.h>
#include <hip/hip_bf16.h>

// ---- int8 path: per-row dynamic quant of x, exact int8 W, i32 MFMA accum ----
#define BM 256
#define BN 256
#define BK 64          // 64 int8 per row per K-tile (2 k-steps of 32)
#define NSLOT 4        // ring of 4 K-tile slots, staged 3 ahead
#define LDS_BYTES (2 * NSLOT * BM * BK)   // 131072 — MUST match launch config

typedef float  f32x4  __attribute__((ext_vector_type(4)));
typedef int    i32x4  __attribute__((ext_vector_type(4)));
typedef int    i32x16 __attribute__((ext_vector_type(16)));
typedef __bf16 bf16x8 __attribute__((ext_vector_type(8)));
typedef __bf16 bf16x4 __attribute__((ext_vector_type(4)));

__device__ __forceinline__ void gload_lds16(const void* g, void* l) {
    __builtin_amdgcn_global_load_lds(
        (const __attribute__((address_space(1))) void*)g,
        (__attribute__((address_space(3))) void*)l, 16, 0, 0);
}

// ------------- prepass 1: per-row absmax quant of x -> int8 + scale ----------
__global__ __launch_bounds__(256)
void rowquant_x(const float* __restrict__ x, signed char* __restrict__ xq,
                float* __restrict__ xs, int K) {
    const int row = blockIdx.x;
    const float* xr = x + (size_t)row * K;
    const int tid = threadIdx.x;
    const int n4 = K / 4;

    float mx = 0.f;
    for (int i = tid; i < n4; i += 256) {
        f32x4 v = ((const f32x4*)xr)[i];
        mx = fmaxf(mx, fmaxf(fmaxf(fabsf(v[0]), fabsf(v[1])),
                             fmaxf(fabsf(v[2]), fabsf(v[3]))));
    }
#pragma unroll
    for (int off = 32; off; off >>= 1)
        mx = fmaxf(mx, __shfl_xor(mx, off));
    __shared__ float smx[4];
    if ((tid & 63) == 0) smx[tid >> 6] = mx;
    __syncthreads();
    mx = fmaxf(fmaxf(smx[0], smx[1]), fmaxf(smx[2], smx[3]));

    const float inv = mx > 0.f ? 127.f / mx : 0.f;
    if (tid == 0) xs[row] = mx / 127.f;

    unsigned* out = (unsigned*)(xq + (size_t)row * K);
    for (int i = tid; i < n4; i += 256) {     // re-read: row is cache-resident
        f32x4 v = ((const f32x4*)xr)[i];
        int q0 = __float2int_rn(v[0] * inv);
        int q1 = __float2int_rn(v[1] * inv);
        int q2 = __float2int_rn(v[2] * inv);
        int q3 = __float2int_rn(v[3] * inv);
        out[i] = (unsigned)(q0 & 255) | ((unsigned)(q1 & 255) << 8) |
                 ((unsigned)(q2 & 255) << 16) | ((unsigned)(q3 & 255) << 24);
    }
}

// ------------- prepass 2: pack W int32 -> int8 (exact) -----------------------
__global__ __launch_bounds__(256)
void cvt_w_i8(const int* __restrict__ w, unsigned* __restrict__ wq, int n4) {
    int i = blockIdx.x * 256 + threadIdx.x;
    const int stride = gridDim.x * 256;
    for (; i < n4; i += stride) {
        i32x4 v = ((const i32x4*)w)[i];
        wq[i] = (unsigned)(v[0] & 255) | ((unsigned)(v[1] & 255) << 8) |
                ((unsigned)(v[2] & 255) << 16) | ((unsigned)(v[3] & 255) << 24);
    }
}

// ------------- main GEMM: i8 32x32x32 MFMA, CROSS-SIMD wave stagger ----------
// LDS K-tile slot (per operand): [2 k-steps][256 rows][32 B], 16 KiB.
//   phys(kstep,row,half) = kstep*8192 + row*32 + (half ^ ((row>>3)&1))*16
// gload_lds writes linearly; GLOBAL source carries the inverse swizzle.
//
// R13 model (fits all 5 neutral rounds): an MFMA occupies its SIMD's issue
// port for the full op duration, so NOTHING co-resident on that SIMD can
// issue ds_reads under an MFMA cluster. Intra-wave reordering (R7/R10) and
// intra-SIMD wave stagger (R11/R12) are structurally inert. The only lever
// is CROSS-SIMD: role = (wid & 2) -> SIMD pair {0,1} reads while pair {2,3}
// runs MFMA, then they swap. The CU-shared LDS unit serves the reading pair
// entirely under the other pair's MFMA window.
//   read-first (lo): [bar] R(ks0) M(ks0) R(ks1) M(ks1)
//   mfma-first (hi): [bar] M(pending) R(ks0) R(ks1) M(ks0); pending <- ks1
// Legal: acc is k-commutative (verified R11/R12, absmax unchanged).
// Uniform lgkmcnt(0)+vmcnt+barrier per tile keeps the cross-barrier register
// carry WAR-safe (STAGE(t+3) hits slot (t-1)&3, issued only after barrier t).
// vmcnt ladder (rem = NT-1-t): rem>=2 -> 8, rem==1 -> 4, rem==0 -> 0.

__global__ __launch_bounds__(512, 2)
void qlin_gemm_i8(const signed char* __restrict__ A,  // [M,K] int8 x-quant
                  const signed char* __restrict__ B,  // [N,K] int8 w
                  const float* __restrict__ xs,       // [M] x row scales
                  const float* __restrict__ scale,    // [N]
                  const float* __restrict__ bias,     // [N]
                  float* __restrict__ C, int M, int N, int K) {
    extern __shared__ signed char lds[];
    signed char* lA = lds;                       // [NSLOT][16384]
    signed char* lB = lds + NSLOT * (BM * BK);

    const int NTN = N / BN;
    const int nwg = gridDim.x;
    int bid = blockIdx.x;
    bid = (bid & 7) * (nwg >> 3) + (bid >> 3);   // XCD swizzle (nwg%8==0)
    const int tm = bid / NTN;
    const int tn = bid % NTN;

    const int tid  = threadIdx.x;
    const int lane = tid & 63;
    const int wid  = tid >> 6;     // 0..7
    const int wr   = wid >> 2;     // 0..1  (M half: 128 rows)
    const int wc   = wid & 3;      // 0..3  (N quarter: 64 cols)
    const bool hi  = (wid & 2) != 0;   // role: by SIMD PAIR (cross-SIMD mix)

    // staging map: lane covers row wid*32 + (lane>>1), physical half lane&1
    const int srow  = wid * 32 + (lane >> 1);
    const int shalf = (lane & 1) ^ ((srow >> 3) & 1);   // logical half (inv swz)
    const signed char* Abase = A + (size_t)(tm * BM + srow) * K + shalf * 16;
    const signed char* Bbase = B + (size_t)(tn * BN + srow) * K + shalf * 16;

    const int NT = K / BK;

    auto STAGE_A = [&](int t) {
        signed char* d = lA + (t & (NSLOT - 1)) * (BM * BK) + wid * 1024;
#pragma unroll
        for (int j = 0; j < 2; ++j)   // j = k-step
            gload_lds16(Abase + t * BK + j * 32, d + j * 8192);
    };
    auto STAGE_B = [&](int t) {
        signed char* d = lB + (t & (NSLOT - 1)) * (BM * BK) + wid * 1024;
#pragma unroll
        for (int j = 0; j < 2; ++j)
            gload_lds16(Bbase + t * BK + j * 32, d + j * 8192);
    };

    const int fr = lane & 31;      // M/N row within 32x32 fragment
    const int fh = lane >> 5;      // k-half selector (16 B)
    const int swz = (fr >> 3) & 1; // row-bit3 slot swizzle
    const int ho = ((fh ^ swz) << 4);

    auto READ_A = [&](const signed char* base, int ks, i32x4* fa) {
        const int o = ks * 8192 + ho;
#pragma unroll
        for (int mi = 0; mi < 4; ++mi) {
            const int R = wr * 128 + mi * 32 + fr;
            fa[mi] = *(const i32x4*)(base + R * 32 + o);
        }
    };
    auto READ_B = [&](const signed char* base, int ks, i32x4* fb) {
        const int o = ks * 8192 + ho;
#pragma unroll
        for (int ni = 0; ni < 2; ++ni) {
            const int R = wc * 64 + ni * 32 + fr;
            fb[ni] = *(const i32x4*)(base + R * 32 + o);
        }
    };

    i32x16 acc[4][2];
#pragma unroll
    for (int mi = 0; mi < 4; ++mi)
#pragma unroll
        for (int ni = 0; ni < 2; ++ni)
#pragma unroll
            for (int r = 0; r < 16; ++r) acc[mi][ni][r] = 0;

    auto MFMA8 = [&](const i32x4* fa, const i32x4* fb) {
        __builtin_amdgcn_s_setprio(1);
#pragma unroll
        for (int mi = 0; mi < 4; ++mi)
#pragma unroll
            for (int ni = 0; ni < 2; ++ni)
                acc[mi][ni] = __builtin_amdgcn_mfma_i32_32x32x32_i8(
                    fa[mi], fb[ni], acc[mi][ni], 0, 0, 0);
        __builtin_amdgcn_s_setprio(0);
    };

    // prologue: stage tiles 0..2 (no barrier here; loop top gates tile 0)
    for (int u = 0; u < 3 && u < NT; ++u) { STAGE_A(u); STAGE_B(u); }

    i32x4 a0[4], b0[2], a1[4], b1[2];   // a1/b1 = hi waves' pending set

    for (int t = 0; t < NT; ++t) {
        const signed char* lAs = lA + (t & (NSLOT - 1)) * (BM * BK);
        const signed char* lBs = lB + (t & (NSLOT - 1)) * (BM * BK);
        const int rem = NT - 1 - t;

        // uniform sync point: all prior ds_reads drained (cross-barrier
        // register carry is then WAR-safe), tile t staged (vmcnt ladder)
        asm volatile("s_waitcnt lgkmcnt(0)" ::: "memory");
        if (rem >= 2)      asm volatile("s_waitcnt vmcnt(8)" ::: "memory");
        else if (rem == 1) asm volatile("s_waitcnt vmcnt(4)" ::: "memory");
        else               asm volatile("s_waitcnt vmcnt(0)" ::: "memory");
        __builtin_amdgcn_s_barrier();

        if (!hi) {
            // read-first pair (SIMDs 0/1): LDS window under partners' MFMA
            READ_A(lAs, 0, a0); READ_B(lBs, 0, b0);
            if (t + 3 < NT) STAGE_A(t + 3);
            MFMA8(a0, b0);
            READ_A(lAs, 1, a0); READ_B(lBs, 1, b0);
            if (t + 3 < NT) STAGE_B(t + 3);
            MFMA8(a0, b0);
        } else {
            // MFMA-first pair (SIMDs 2/3): pending cluster while partners read
            if (t > 0) MFMA8(a1, b1);
            if (t + 3 < NT) STAGE_A(t + 3);
            READ_A(lAs, 0, a0); READ_B(lBs, 0, b0);
            READ_A(lAs, 1, a1); READ_B(lBs, 1, b1);   // pending for t+1
            if (t + 3 < NT) STAGE_B(t + 3);
            MFMA8(a0, b0);
        }
    }
    if (hi) MFMA8(a1, b1);   // flush pending (NT-1, ks1)

    // epilogue: 32x32 C/D layout: col = lane&31, row = (r&3)+8*(r>>2)+4*(lane>>5)
    const int rb = tm * BM + wr * 128 + 4 * fh;
    const int cb = tn * BN + wc * 64 + fr;
#pragma unroll
    for (int mi = 0; mi < 4; ++mi) {
        float sm[16];
#pragma unroll
        for (int r = 0; r < 16; ++r)
            sm[r] = xs[rb + mi * 32 + (r & 3) + 8 * (r >> 2)];
#pragma unroll
        for (int ni = 0; ni < 2; ++ni) {
            const int n = cb + ni * 32;
            const float sc = scale[n];
            const float bs = bias[n];
#pragma unroll
            for (int r = 0; r < 16; ++r) {
                const int m = rb + mi * 32 + (r & 3) + 8 * (r >> 2);
                C[(size_t)m * N + n] = fmaf((float)acc[mi][ni][r], sm[r] * sc, bs);
            }
        }
    }
}

// ---------------- fallback (reg-staged 128^2 bf16, any shape) ----------------
#define FBM 128
#define FBK 32

__device__ __forceinline__ int swz_elem(int row, int e) {
    return row * FBK + (e ^ (((row >> 1) & 3) << 3));
}

__global__ __launch_bounds__(256, 2)
void qlin_gemm_reg(const float* __restrict__ A, const int* __restrict__ W,
                   const float* __restrict__ scale, const float* __restrict__ bias,
                   float* __restrict__ C, int M, int N, int K) {
    __shared__ __bf16 lA[2][FBM * FBK];
    __shared__ __bf16 lB[2][FBM * FBK];
    const int NTN = N / FBM;
    const int nwg = gridDim.x;
    int bid = blockIdx.x;
    if ((nwg & 7) == 0) bid = (bid & 7) * (nwg >> 3) + (bid >> 3);
    const int tm = bid / NTN, tn = bid % NTN;
    const int tid = threadIdx.x, lane = tid & 63, wid = tid >> 6;
    const int wr = wid >> 1, wc = wid & 1;
    const int srow0 = tid >> 3, skq = tid & 7;
    const float* aptr = A + (size_t)(tm * FBM + srow0) * K + skq * 4;
    const int*   wptr = W + (size_t)(tn * FBM + srow0) * K + skq * 4;
    const size_t rstride = (size_t)32 * K;
    f32x4 sa[4]; i32x4 sw[4];
    auto LOAD = [&](int t) {
#pragma unroll
        for (int j = 0; j < 4; ++j) {
            sa[j] = *(const f32x4*)(aptr + (size_t)t * FBK + j * rstride);
            sw[j] = *(const i32x4*)(wptr + (size_t)t * FBK + j * rstride);
        }
    };
    auto STORE = [&](int buf) {
#pragma unroll
        for (int j = 0; j < 4; ++j) {
            const int idx = swz_elem(srow0 + j * 32, skq * 4);
            bf16x4 va = { (__bf16)sa[j][0], (__bf16)sa[j][1],
                          (__bf16)sa[j][2], (__bf16)sa[j][3] };
            bf16x4 vw = { (__bf16)(float)sw[j][0], (__bf16)(float)sw[j][1],
                          (__bf16)(float)sw[j][2], (__bf16)(float)sw[j][3] };
            *(bf16x4*)&lA[buf][idx] = va;
            *(bf16x4*)&lB[buf][idx] = vw;
        }
    };
    const f32x4 fzero = {0.f, 0.f, 0.f, 0.f};
    f32x4 acc[4][4];
#pragma unroll
    for (int i = 0; i < 4; ++i)
#pragma unroll
        for (int j = 0; j < 4; ++j) acc[i][j] = fzero;
    const int fr = lane & 15, fks = (lane >> 4) * 8;
    LOAD(0); STORE(0); __syncthreads();
    const int NT = K / FBK;
    for (int t = 0; t < NT; ++t) {
        const int buf = t & 1;
        if (t + 1 < NT) LOAD(t + 1);
        bf16x8 af[4], bfg[4];
#pragma unroll
        for (int mi = 0; mi < 4; ++mi)
            af[mi] = *(const bf16x8*)&lA[buf][swz_elem(wr * 64 + mi * 16 + fr, fks)];
#pragma unroll
        for (int ni = 0; ni < 4; ++ni)
            bfg[ni] = *(const bf16x8*)&lB[buf][swz_elem(wc * 64 + ni * 16 + fr, fks)];
#pragma unroll
        for (int mi = 0; mi < 4; ++mi)
#pragma unroll
            for (int ni = 0; ni < 4; ++ni)
                acc[mi][ni] = __builtin_amdgcn_mfma_f32_16x16x32_bf16(
                    af[mi], bfg[ni], acc[mi][ni], 0, 0, 0);
        if (t + 1 < NT) STORE(buf ^ 1);
        __syncthreads();
    }
    const int row0 = tm * FBM + wr * 64 + (lane >> 4) * 4;
    const int col0 = tn * FBM + wc * 64 + fr;
#pragma unroll
    for (int ni = 0; ni < 4; ++ni) {
        const int n = col0 + ni * 16;
        const float sc = scale[n], bs = bias[n];
#pragma unroll
        for (int mi = 0; mi < 4; ++mi) {
            const int m = row0 + mi * 16;
#pragma unroll
            for (int r = 0; r < 4; ++r)
                C[(size_t)(m + r) * N + n] = fmaf(acc[mi][ni][r], sc, bs);
        }
    }
}

extern "C" void kernel_launch(void* const* d_in, const int* in_sizes, int n_in,
                              void* d_out, int out_size, void* d_ws, size_t ws_size,
                              hipStream_t stream) {
    const float* x     = (const float*)d_in[0];
    const int*   w8    = (const int*)d_in[1];
    const float* scale = (const float*)d_in[2];
    const float* bias  = (const float*)d_in[3];
    float*       out   = (float*)d_out;

    const int DOUT = in_sizes[2];
    const int DIN  = in_sizes[1] / DOUT;
    const int M    = in_sizes[0] / DIN;

    const size_t need = (size_t)M * DIN + (size_t)DOUT * DIN + (size_t)M * 4;
    const int nwg = (M / BM) * (DOUT / BN);
    const bool ok = (ws_size >= need) && (M % BM == 0) && (DOUT % BN == 0) &&
                    (DIN % BK == 0) && (nwg % 8 == 0) && (DIN / BK >= 4);
    if (ok) {
        signed char* xq = (signed char*)d_ws;
        signed char* wq = xq + (size_t)M * DIN;
        float*       xs = (float*)(wq + (size_t)DOUT * DIN);
        rowquant_x<<<M, 256, 0, stream>>>(x, xq, xs, DIN);
        cvt_w_i8<<<2048, 256, 0, stream>>>(w8, (unsigned*)wq, DOUT * DIN / 4);
        hipFuncSetAttribute(reinterpret_cast<const void*>(qlin_gemm_i8),
                            hipFuncAttributeMaxDynamicSharedMemorySize, LDS_BYTES);
        qlin_gemm_i8<<<nwg, 512, LDS_BYTES, stream>>>(xq, wq, xs, scale, bias, out,
                                                      M, DOUT, DIN);
    } else {
        dim3 grid((M / FBM) * (DOUT / FBM));
        qlin_gemm_reg<<<grid, 256, 0, stream>>>(x, w8, scale, bias, out, M, DOUT, DIN);
    }
}

// Round 14
// 190.905 us; speedup vs baseline: 1.0927x; 1.0927x over previous
//
#include <hip/hip_runtime.h>
#include <hip/hip_bf16.h>

// ---- int8 path: per-row dynamic quant of x, exact int8 W, i32 MFMA accum ----
// R14: switch MFMA shape 32x32x32 -> 16x16x64 (same FLOPs, half the per-
// instruction SIMD issue-block). Session A/B evidence: bf16@16x16 ran 50%
// MfmaUtil (R4); i8@32x32 ran 39% (R5-R13) across 6 schedule variants.
#define BM 256
#define BN 256
#define BK 64          // 64 int8 per row per K-tile = one K=64 MFMA step
#define NSLOT 4        // ring of 4 K-tile slots, staged 3 ahead
#define LDS_BYTES (2 * NSLOT * BM * BK)   // 131072 — MUST match launch config

typedef float  f32x4  __attribute__((ext_vector_type(4)));
typedef int    i32x4  __attribute__((ext_vector_type(4)));
typedef __bf16 bf16x8 __attribute__((ext_vector_type(8)));
typedef __bf16 bf16x4 __attribute__((ext_vector_type(4)));

__device__ __forceinline__ void gload_lds16(const void* g, void* l) {
    __builtin_amdgcn_global_load_lds(
        (const __attribute__((address_space(1))) void*)g,
        (__attribute__((address_space(3))) void*)l, 16, 0, 0);
}

// ------------- prepass 1: per-row absmax quant of x -> int8 + scale ----------
__global__ __launch_bounds__(256)
void rowquant_x(const float* __restrict__ x, signed char* __restrict__ xq,
                float* __restrict__ xs, int K) {
    const int row = blockIdx.x;
    const float* xr = x + (size_t)row * K;
    const int tid = threadIdx.x;
    const int n4 = K / 4;

    float mx = 0.f;
    for (int i = tid; i < n4; i += 256) {
        f32x4 v = ((const f32x4*)xr)[i];
        mx = fmaxf(mx, fmaxf(fmaxf(fabsf(v[0]), fabsf(v[1])),
                             fmaxf(fabsf(v[2]), fabsf(v[3]))));
    }
#pragma unroll
    for (int off = 32; off; off >>= 1)
        mx = fmaxf(mx, __shfl_xor(mx, off));
    __shared__ float smx[4];
    if ((tid & 63) == 0) smx[tid >> 6] = mx;
    __syncthreads();
    mx = fmaxf(fmaxf(smx[0], smx[1]), fmaxf(smx[2], smx[3]));

    const float inv = mx > 0.f ? 127.f / mx : 0.f;
    if (tid == 0) xs[row] = mx / 127.f;

    unsigned* out = (unsigned*)(xq + (size_t)row * K);
    for (int i = tid; i < n4; i += 256) {     // re-read: row is cache-resident
        f32x4 v = ((const f32x4*)xr)[i];
        int q0 = __float2int_rn(v[0] * inv);
        int q1 = __float2int_rn(v[1] * inv);
        int q2 = __float2int_rn(v[2] * inv);
        int q3 = __float2int_rn(v[3] * inv);
        out[i] = (unsigned)(q0 & 255) | ((unsigned)(q1 & 255) << 8) |
                 ((unsigned)(q2 & 255) << 16) | ((unsigned)(q3 & 255) << 24);
    }
}

// ------------- prepass 2: pack W int32 -> int8 (exact) -----------------------
__global__ __launch_bounds__(256)
void cvt_w_i8(const int* __restrict__ w, unsigned* __restrict__ wq, int n4) {
    int i = blockIdx.x * 256 + threadIdx.x;
    const int stride = gridDim.x * 256;
    for (; i < n4; i += stride) {
        i32x4 v = ((const i32x4*)w)[i];
        wq[i] = (unsigned)(v[0] & 255) | ((unsigned)(v[1] & 255) << 8) |
                ((unsigned)(v[2] & 255) << 16) | ((unsigned)(v[3] & 255) << 24);
    }
}

// ------------- main GEMM: i8 16x16x64 MFMA, free-run counted-vmcnt ring ------
// LDS K-tile slot (per operand): row-major [256 rows][64 B], 16 KiB.
//   phys 16B-quad of row R: q_phys = q ^ ((R>>1)&3)  (R2-proven swizzle).
// Frag read (16x16x64): lane l -> row fr=l&15, k-quad kq=l>>4; a wave covers
// 16 rows x 64 B; with the swizzle, each 32-lane phase spreads 2-way over
// all banks (free, m136). gload_lds dest linear (lane*16): lane covers row
// wid*32 + j*16 + (l>>2), quad l&3; GLOBAL source carries inverse swizzle.
// Schedule (R7 skeleton, isolates the shape variable): per tile one
// vmcnt-laddered barrier, all 12 ds_reads upfront, STAGE(t+3), then a
// single setprio-bracketed 32-MFMA cluster (all-independent accs).
// vmcnt ladder (rem = NT-1-t): rem>=2 -> 8, rem==1 -> 4, rem==0 -> 0.
// WAR: STAGE(t+3) hits slot (t-1)&3, issued only after barrier t; tile
// t-1's reads were consumed (compiler lgkm waits) before that barrier.

__global__ __launch_bounds__(512, 2)
void qlin_gemm_i8(const signed char* __restrict__ A,  // [M,K] int8 x-quant
                  const signed char* __restrict__ B,  // [N,K] int8 w
                  const float* __restrict__ xs,       // [M] x row scales
                  const float* __restrict__ scale,    // [N]
                  const float* __restrict__ bias,     // [N]
                  float* __restrict__ C, int M, int N, int K) {
    extern __shared__ signed char lds[];
    signed char* lA = lds;                       // [NSLOT][256*64]
    signed char* lB = lds + NSLOT * (BM * BK);

    const int NTN = N / BN;
    const int nwg = gridDim.x;
    int bid = blockIdx.x;
    bid = (bid & 7) * (nwg >> 3) + (bid >> 3);   // XCD swizzle (nwg%8==0)
    const int tm = bid / NTN;
    const int tn = bid % NTN;

    const int tid  = threadIdx.x;
    const int lane = tid & 63;
    const int wid  = tid >> 6;     // 0..7
    const int wr   = wid >> 2;     // 0..1  (M half: 128 rows)
    const int wc   = wid & 3;      // 0..3  (N quarter: 64 cols)

    // staging map: per j (0,1) lane covers row wid*32 + j*16 + (lane>>2),
    // physical quad lane&3; inverse swizzle on the global source quad.
    const int srow0 = wid * 32 + (lane >> 2);
    const int srow1 = srow0 + 16;
    const int gq0 = (lane & 3) ^ ((srow0 >> 1) & 3);
    const int gq1 = (lane & 3) ^ ((srow1 >> 1) & 3);
    const signed char* Ap0 = A + (size_t)(tm * BM + srow0) * K + gq0 * 16;
    const signed char* Ap1 = A + (size_t)(tm * BM + srow1) * K + gq1 * 16;
    const signed char* Bp0 = B + (size_t)(tn * BN + srow0) * K + gq0 * 16;
    const signed char* Bp1 = B + (size_t)(tn * BN + srow1) * K + gq1 * 16;

    const int NT = K / BK;

    auto STAGE_A = [&](int t) {
        signed char* d = lA + (t & (NSLOT - 1)) * (BM * BK) + wid * 2048;
        gload_lds16(Ap0 + t * BK, d);
        gload_lds16(Ap1 + t * BK, d + 1024);
    };
    auto STAGE_B = [&](int t) {
        signed char* d = lB + (t & (NSLOT - 1)) * (BM * BK) + wid * 2048;
        gload_lds16(Bp0 + t * BK, d);
        gload_lds16(Bp1 + t * BK, d + 1024);
    };

    const int fr = lane & 15;      // row within 16x16 fragment
    const int kq = lane >> 4;      // k-quad 0..3 (16 B each)

    // frag LDS offsets: row R, phys quad = kq ^ ((R>>1)&3)
    auto AOFF = [&](int mi) {
        const int R = wr * 128 + mi * 16 + fr;
        return R * 64 + ((kq ^ ((R >> 1) & 3)) << 4);
    };
    auto BOFF = [&](int ni) {
        const int R = wc * 64 + ni * 16 + fr;
        return R * 64 + ((kq ^ ((R >> 1) & 3)) << 4);
    };

    i32x4 acc[8][4];
#pragma unroll
    for (int mi = 0; mi < 8; ++mi)
#pragma unroll
        for (int ni = 0; ni < 4; ++ni) {
            acc[mi][ni][0] = 0; acc[mi][ni][1] = 0;
            acc[mi][ni][2] = 0; acc[mi][ni][3] = 0;
        }

    // prologue: stage tiles 0..2 (12 loads/thread total)
    for (int u = 0; u < 3 && u < NT; ++u) { STAGE_A(u); STAGE_B(u); }

    for (int t = 0; t < NT; ++t) {
        const signed char* lAs = lA + (t & (NSLOT - 1)) * (BM * BK);
        const signed char* lBs = lB + (t & (NSLOT - 1)) * (BM * BK);
        const int rem = NT - 1 - t;

        if (rem >= 2)      asm volatile("s_waitcnt vmcnt(8)" ::: "memory");
        else if (rem == 1) asm volatile("s_waitcnt vmcnt(4)" ::: "memory");
        else               asm volatile("s_waitcnt vmcnt(0)" ::: "memory");
        __builtin_amdgcn_s_barrier();   // only barrier this K-tile

        // ---- all 12 ds_reads upfront ----
        i32x4 af[8], bf[4];
#pragma unroll
        for (int mi = 0; mi < 8; ++mi)
            af[mi] = *(const i32x4*)(lAs + AOFF(mi));
#pragma unroll
        for (int ni = 0; ni < 4; ++ni)
            bf[ni] = *(const i32x4*)(lBs + BOFF(ni));

        // stage issue sits in the ds_read latency shadow
        if (t + 3 < NT) { STAGE_A(t + 3); STAGE_B(t + 3); }

        // ---- single 32-MFMA cluster (all independent accumulators) ----
        __builtin_amdgcn_s_setprio(1);
#pragma unroll
        for (int mi = 0; mi < 8; ++mi)
#pragma unroll
            for (int ni = 0; ni < 4; ++ni)
                acc[mi][ni] = __builtin_amdgcn_mfma_i32_16x16x64_i8(
                    af[mi], bf[ni], acc[mi][ni], 0, 0, 0);
        __builtin_amdgcn_s_setprio(0);
    }

    // epilogue: 16x16 C/D layout: col = lane&15, row = (lane>>4)*4 + r
    const int rb = tm * BM + wr * 128 + (lane >> 4) * 4;
    const int cb = tn * BN + wc * 64 + fr;
#pragma unroll
    for (int mi = 0; mi < 8; ++mi) {
        const int m0 = rb + mi * 16;
        float sm[4];
#pragma unroll
        for (int r = 0; r < 4; ++r) sm[r] = xs[m0 + r];
#pragma unroll
        for (int ni = 0; ni < 4; ++ni) {
            const int n = cb + ni * 16;
            const float sc = scale[n];
            const float bs = bias[n];
#pragma unroll
            for (int r = 0; r < 4; ++r)
                C[(size_t)(m0 + r) * N + n] =
                    fmaf((float)acc[mi][ni][r], sm[r] * sc, bs);
        }
    }
}

// ---------------- fallback (reg-staged 128^2 bf16, any shape) ----------------
#define FBM 128
#define FBK 32

__device__ __forceinline__ int swz_elem(int row, int e) {
    return row * FBK + (e ^ (((row >> 1) & 3) << 3));
}

__global__ __launch_bounds__(256, 2)
void qlin_gemm_reg(const float* __restrict__ A, const int* __restrict__ W,
                   const float* __restrict__ scale, const float* __restrict__ bias,
                   float* __restrict__ C, int M, int N, int K) {
    __shared__ __bf16 lA[2][FBM * FBK];
    __shared__ __bf16 lB[2][FBM * FBK];
    const int NTN = N / FBM;
    const int nwg = gridDim.x;
    int bid = blockIdx.x;
    if ((nwg & 7) == 0) bid = (bid & 7) * (nwg >> 3) + (bid >> 3);
    const int tm = bid / NTN, tn = bid % NTN;
    const int tid = threadIdx.x, lane = tid & 63, wid = tid >> 6;
    const int wr = wid >> 1, wc = wid & 1;
    const int srow0 = tid >> 3, skq = tid & 7;
    const float* aptr = A + (size_t)(tm * FBM + srow0) * K + skq * 4;
    const int*   wptr = W + (size_t)(tn * FBM + srow0) * K + skq * 4;
    const size_t rstride = (size_t)32 * K;
    f32x4 sa[4]; i32x4 sw[4];
    auto LOAD = [&](int t) {
#pragma unroll
        for (int j = 0; j < 4; ++j) {
            sa[j] = *(const f32x4*)(aptr + (size_t)t * FBK + j * rstride);
            sw[j] = *(const i32x4*)(wptr + (size_t)t * FBK + j * rstride);
        }
    };
    auto STORE = [&](int buf) {
#pragma unroll
        for (int j = 0; j < 4; ++j) {
            const int idx = swz_elem(srow0 + j * 32, skq * 4);
            bf16x4 va = { (__bf16)sa[j][0], (__bf16)sa[j][1],
                          (__bf16)sa[j][2], (__bf16)sa[j][3] };
            bf16x4 vw = { (__bf16)(float)sw[j][0], (__bf16)(float)sw[j][1],
                          (__bf16)(float)sw[j][2], (__bf16)(float)sw[j][3] };
            *(bf16x4*)&lA[buf][idx] = va;
            *(bf16x4*)&lB[buf][idx] = vw;
        }
    };
    const f32x4 fzero = {0.f, 0.f, 0.f, 0.f};
    f32x4 acc[4][4];
#pragma unroll
    for (int i = 0; i < 4; ++i)
#pragma unroll
        for (int j = 0; j < 4; ++j) acc[i][j] = fzero;
    const int fr = lane & 15, fks = (lane >> 4) * 8;
    LOAD(0); STORE(0); __syncthreads();
    const int NT = K / FBK;
    for (int t = 0; t < NT; ++t) {
        const int buf = t & 1;
        if (t + 1 < NT) LOAD(t + 1);
        bf16x8 af[4], bfg[4];
#pragma unroll
        for (int mi = 0; mi < 4; ++mi)
            af[mi] = *(const bf16x8*)&lA[buf][swz_elem(wr * 64 + mi * 16 + fr, fks)];
#pragma unroll
        for (int ni = 0; ni < 4; ++ni)
            bfg[ni] = *(const bf16x8*)&lB[buf][swz_elem(wc * 64 + ni * 16 + fr, fks)];
#pragma unroll
        for (int mi = 0; mi < 4; ++mi)
#pragma unroll
            for (int ni = 0; ni < 4; ++ni)
                acc[mi][ni] = __builtin_amdgcn_mfma_f32_16x16x32_bf16(
                    af[mi], bfg[ni], acc[mi][ni], 0, 0, 0);
        if (t + 1 < NT) STORE(buf ^ 1);
        __syncthreads();
    }
    const int row0 = tm * FBM + wr * 64 + (lane >> 4) * 4;
    const int col0 = tn * FBM + wc * 64 + fr;
#pragma unroll
    for (int ni = 0; ni < 4; ++ni) {
        const int n = col0 + ni * 16;
        const float sc = scale[n], bs = bias[n];
#pragma unroll
        for (int mi = 0; mi < 4; ++mi) {
            const int m = row0 + mi * 16;
#pragma unroll
            for (int r = 0; r < 4; ++r)
                C[(size_t)(m + r) * N + n] = fmaf(acc[mi][ni][r], sc, bs);
        }
    }
}

extern "C" void kernel_launch(void* const* d_in, const int* in_sizes, int n_in,
                              void* d_out, int out_size, void* d_ws, size_t ws_size,
                              hipStream_t stream) {
    const float* x     = (const float*)d_in[0];
    const int*   w8    = (const int*)d_in[1];
    const float* scale = (const float*)d_in[2];
    const float* bias  = (const float*)d_in[3];
    float*       out   = (float*)d_out;

    const int DOUT = in_sizes[2];
    const int DIN  = in_sizes[1] / DOUT;
    const int M    = in_sizes[0] / DIN;

    const size_t need = (size_t)M * DIN + (size_t)DOUT * DIN + (size_t)M * 4;
    const int nwg = (M / BM) * (DOUT / BN);
    const bool ok = (ws_size >= need) && (M % BM == 0) && (DOUT % BN == 0) &&
                    (DIN % BK == 0) && (nwg % 8 == 0) && (DIN / BK >= 4);
    if (ok) {
        signed char* xq = (signed char*)d_ws;
        signed char* wq = xq + (size_t)M * DIN;
        float*       xs = (float*)(wq + (size_t)DOUT * DIN);
        rowquant_x<<<M, 256, 0, stream>>>(x, xq, xs, DIN);
        cvt_w_i8<<<2048, 256, 0, stream>>>(w8, (unsigned*)wq, DOUT * DIN / 4);
        hipFuncSetAttribute(reinterpret_cast<const void*>(qlin_gemm_i8),
                            hipFuncAttributeMaxDynamicSharedMemorySize, LDS_BYTES);
        qlin_gemm_i8<<<nwg, 512, LDS_BYTES, stream>>>(xq, wq, xs, scale, bias, out,
                                                      M, DOUT, DIN);
    } else {
        dim3 grid((M / FBM) * (DOUT / FBM));
        qlin_gemm_reg<<<grid, 256, 0, stream>>>(x, w8, scale, bias, out, M, DOUT, DIN);
    }
}